// Round 1
// baseline (577.936 us; speedup 1.0000x reference)
//
#include <hip/hip_runtime.h>
#include <hip/hip_bf16.h>

// FlyLoRALinear fused single-kernel:
//   out = (top8-mask(|x@A^T + d|) * (x@A^T)) @ B^T * 2
// x:[4,4096,4096]f32  A:[32,4096]f32  B:[4096,32]f32  d:[32]f32  out:[4,4096,4096]f32
#define IN_F   4096
#define RDIM   32
#define KSEL   8
#define OUT_F  4096
#define TOK    16      // tokens per WG
#define CHUNK  512     // k-elements staged per chunk
#define NCHUNK (IN_F / CHUNK)   // 8

typedef float  f4  __attribute__((ext_vector_type(4)));
typedef short  s8  __attribute__((ext_vector_type(8)));   // bf16x8 MFMA frag
typedef float  cf4 __attribute__((ext_vector_type(4)));   // MFMA accum

__device__ inline short f2bf(float f) {
  __hip_bfloat16 h = __float2bfloat16(f);
  return *reinterpret_cast<short*>(&h);
}

// Stage one [16 tok][512 k] fp32 chunk (32 KB) via global_load_lds width-16.
// LDS layout is linear in (p*256+tid)*16B == wave-uniform base + lane*16  ✓
__device__ inline void stage_chunk(const float* __restrict__ x, int m0, int kb,
                                   float* dst, int tid) {
  #pragma unroll
  for (int p = 0; p < 8; ++p) {
    const int off = (p * 256 + tid) * 16;          // byte offset in chunk
    const int t   = off >> 11;                     // 2048 B per token row
    const float* g = x + (size_t)(m0 + t) * IN_F + kb + ((off & 2047) >> 2);
    __builtin_amdgcn_global_load_lds(
        (const __attribute__((address_space(1))) void*)g,
        (__attribute__((address_space(3))) void*)(dst + (off >> 2)),
        16, 0, 0);
  }
}

__global__ __launch_bounds__(256, 2) void fused_flylora(
    const float* __restrict__ x, const float* __restrict__ A,
    const float* __restrict__ B, const float* __restrict__ dbias,
    float* __restrict__ out)
{
  // xs: double-buffered x stage (2 x 32 KB). After phase 1, xs[0] is aliased
  // as the cross-lane reduction scratch (4 waves x 32 accs x 66 floats).
  __shared__ __align__(16) float xs[2][TOK * CHUNK];
  __shared__ double score[TOK][RDIM];
  __shared__ float  yval[TOK][RDIM];
  __shared__ __align__(16) short Zl[TOK * RDIM];   // bf16, SCALE=2 folded in

  const int tid  = threadIdx.x;
  const int lane = tid & 63;
  const int w    = tid >> 6;
  const int m0   = blockIdx.x * TOK;

  // ---------------- phase 1: y = x @ A^T (fp32 FMA, fp64 reduce) -----------
  stage_chunk(x, m0, 0, xs[0], tid);

  float acc[TOK][8];
  #pragma unroll
  for (int t = 0; t < TOK; ++t)
    #pragma unroll
    for (int j = 0; j < 8; ++j) acc[t][j] = 0.f;

  const float* Abase = A + (size_t)(8 * w) * IN_F;   // wave w owns r = 8w..8w+7

  int cur = 0;
  for (int c = 0; c < NCHUNK; ++c) {
    __syncthreads();                         // chunk c landed (vmcnt drained)
    if (c + 1 < NCHUNK)                      // prefetch next chunk async
      stage_chunk(x, m0, (c + 1) * CHUNK, xs[cur ^ 1], tid);

    const int kbase = c * CHUNK;
    const float* xsc = xs[cur];
    #pragma unroll
    for (int i = 0; i < 2; ++i) {
      const int kk = 256 * i + 4 * lane;
      f4 av[8];
      #pragma unroll
      for (int j = 0; j < 8; ++j)
        av[j] = *(const f4*)(Abase + (size_t)j * IN_F + kbase + kk);
      #pragma unroll
      for (int t = 0; t < TOK; ++t) {
        f4 xv = *(const f4*)&xsc[t * CHUNK + kk];
        #pragma unroll
        for (int j = 0; j < 8; ++j) {
          acc[t][j] = fmaf(xv.x, av[j].x, acc[t][j]);
          acc[t][j] = fmaf(xv.y, av[j].y, acc[t][j]);
          acc[t][j] = fmaf(xv.z, av[j].z, acc[t][j]);
          acc[t][j] = fmaf(xv.w, av[j].w, acc[t][j]);
        }
      }
    }
    cur ^= 1;
  }
  __syncthreads();                           // xs dead -> reduction scratch

  // Cross-lane reduce: 128 accs/lane, 4 rounds of 32. Stride 66 -> bank =
  // 2a%32, 2-way (free). fp64 final sum: deterministic, matches exact top-k.
  float* red = (float*)xs + w * 2112;        // 32*66 floats per wave
  #pragma unroll
  for (int h = 0; h < 4; ++h) {
    #pragma unroll
    for (int a = 0; a < 32; ++a)
      red[a * 66 + lane] = acc[4 * h + (a >> 3)][a & 7];
    __syncthreads();
    if (lane < 32) {
      double s = 0.0;
      #pragma unroll
      for (int m = 0; m < 64; ++m) s += (double)red[lane * 66 + m];
      int t = 4 * h + (lane >> 3);
      int r = 8 * w + (lane & 7);
      double b = s + (double)dbias[r];
      score[t][r] = fabs(b);
      yval[t][r]  = (float)s;
    }
    __syncthreads();
  }

  // ---------------- phase 2: rank-based top-8 (== jax.lax.top_k) -----------
  #pragma unroll
  for (int rep = 0; rep < 2; ++rep) {
    int idx = rep * 256 + tid;               // 512 (t,i) pairs
    int t = idx >> 5, i = idx & 31;
    double si = score[t][i];
    int rank = 0;
    #pragma unroll
    for (int j = 0; j < RDIM; ++j) {
      double sj = score[t][j];
      rank += (sj > si) || (sj == si && j < i);
    }
    float z = (rank < KSEL) ? yval[t][i] * 2.0f : 0.0f;   // fold SCALE=2
    Zl[t * RDIM + i] = f2bf(z);
  }
  __syncthreads();

  // ---------------- phase 3: out = Z @ B^T via mfma_f32_16x16x32_bf16 ------
  // Wave w covers cols [1024w, 1024w+1024) for the WG's 16 tokens.
  // Same fragment/D layout as the previously verified k2.
  {
    const int rr = lane & 15;                // A: token row, B: o-col; D col
    const int q  = lane >> 4;                // k-block 8q..8q+8
    const int nb = w * 1024;
    s8 a = *(const s8*)&Zl[rr * RDIM + q * 8];
    const float* Bp = B + (size_t)(nb + rr) * RDIM + q * 8;
    float* op = out + (size_t)(m0 + q * 4) * OUT_F + nb + rr;

    #pragma unroll
    for (int tile = 0; tile < 64; ++tile) {
      const float* bp = Bp + (size_t)tile * 16 * RDIM;
      f4 b0 = *(const f4*)bp;
      f4 b1 = *(const f4*)(bp + 4);
      s8 b;
      b[0] = f2bf(b0.x); b[1] = f2bf(b0.y); b[2] = f2bf(b0.z); b[3] = f2bf(b0.w);
      b[4] = f2bf(b1.x); b[5] = f2bf(b1.y); b[6] = f2bf(b1.z); b[7] = f2bf(b1.w);
      cf4 d = {0.f, 0.f, 0.f, 0.f};
      d = __builtin_amdgcn_mfma_f32_16x16x32_bf16(a, b, d, 0, 0, 0);
      // D: col = lane&15 (o), row = 4q+reg (token)
      #pragma unroll
      for (int reg = 0; reg < 4; ++reg)
        __builtin_nontemporal_store(d[reg], op + (size_t)reg * OUT_F + tile * 16);
    }
  }
}

extern "C" void kernel_launch(void* const* d_in, const int* in_sizes, int n_in,
                              void* d_out, int out_size, void* d_ws, size_t ws_size,
                              hipStream_t stream) {
  const float* x     = (const float*)d_in[0];
  const float* A     = (const float*)d_in[1];
  const float* B     = (const float*)d_in[2];
  const float* dbias = (const float*)d_in[3];
  float* out = (float*)d_out;
  (void)d_ws; (void)ws_size;

  hipLaunchKernelGGL(fused_flylora, dim3(1024), dim3(256), 0, stream,
                     x, A, B, dbias, out);
}

// Round 2
// 531.296 us; speedup vs baseline: 1.0878x; 1.0878x over previous
//
#include <hip/hip_runtime.h>
#include <hip/hip_bf16.h>

// FlyLoRALinear fused single-kernel:
//   out = (top8-mask(|x@A^T + d|) * (x@A^T)) @ B^T * 2
// x:[4,4096,4096]f32  A:[32,4096]f32  B:[4096,32]f32  d:[32]f32  out:[4,4096,4096]f32
#define IN_F   4096
#define RDIM   32
#define KSEL   8
#define OUT_F  4096
#define TOK    16       // tokens per WG
#define CHUNK  256      // k-elements staged per chunk
#define NCHUNK (IN_F / CHUNK)   // 16
#define NWAVE  8        // 512 threads

typedef float  f4  __attribute__((ext_vector_type(4)));
typedef short  s8  __attribute__((ext_vector_type(8)));   // bf16x8 MFMA frag
typedef float  cf4 __attribute__((ext_vector_type(4)));   // MFMA accum

__device__ inline short f2bf(float f) {
  __hip_bfloat16 h = __float2bfloat16(f);
  return *reinterpret_cast<short*>(&h);
}

// Stage one [16 tok][256 k] fp32 chunk (16 KB) via global_load_lds width-16.
// Dest is wave-uniform base + lane*16 (linear in tid)  ✓
__device__ inline void stage_chunk(const float* __restrict__ x, int m0, int kb,
                                   float* dst, int tid) {
  #pragma unroll
  for (int p = 0; p < 2; ++p) {
    const int off = (p * 512 + tid) * 16;          // byte offset, 0..16K
    const int t   = off >> 10;                     // 1024 B per token row
    const float* g = x + (size_t)(m0 + t) * IN_F + kb + ((off & 1023) >> 2);
    __builtin_amdgcn_global_load_lds(
        (const __attribute__((address_space(1))) void*)g,
        (__attribute__((address_space(3))) void*)(dst + (off >> 2)),
        16, 0, 0);
  }
}

__global__ __launch_bounds__(512, 4) void fused_flylora(
    const float* __restrict__ x, const float* __restrict__ A,
    const float* __restrict__ B, const float* __restrict__ dbias,
    float* __restrict__ out)
{
  __shared__ __align__(16) float xs[2][TOK * CHUNK];   // 32 KB dbuf x-stage
  __shared__ float  red[NWAVE][16][66];                // 33 KB reduce scratch
  __shared__ double score[TOK][RDIM];                  // 4 KB
  __shared__ float  yval[TOK][RDIM];                   // 2 KB
  __shared__ __align__(16) short Zl[TOK * RDIM];       // 1 KB bf16, SCALE folded

  const int tid  = threadIdx.x;      // 0..511
  const int lane = tid & 63;
  const int w    = tid >> 6;         // 0..7
  const int m0   = blockIdx.x * TOK;

  // ---------------- phase 1: y = x @ A^T (fp32 FMA, fp64 reduce) -----------
  stage_chunk(x, m0, 0, xs[0], tid);

  float acc[TOK][4];                 // wave w owns r = 4w..4w+3
  #pragma unroll
  for (int t = 0; t < TOK; ++t)
    #pragma unroll
    for (int j = 0; j < 4; ++j) acc[t][j] = 0.f;

  const float* Abase = A + (size_t)(4 * w) * IN_F;
  const int kk = 4 * lane;           // lane's k-slice within the chunk

  int cur = 0;
  for (int c = 0; c < NCHUNK; ++c) {
    __syncthreads();                 // chunk c landed (barrier drains vmcnt)
    if (c + 1 < NCHUNK)              // prefetch next chunk async into other buf
      stage_chunk(x, m0, (c + 1) * CHUNK, xs[cur ^ 1], tid);

    const float* xsc = xs[cur];
    const int kbase = c * CHUNK;
    f4 av[4];
    #pragma unroll
    for (int j = 0; j < 4; ++j)
      av[j] = *(const f4*)(Abase + (size_t)j * IN_F + kbase + kk);
    #pragma unroll
    for (int t = 0; t < TOK; ++t) {
      f4 xv = *(const f4*)&xsc[t * CHUNK + kk];
      #pragma unroll
      for (int j = 0; j < 4; ++j) {
        acc[t][j] = fmaf(xv.x, av[j].x, acc[t][j]);
        acc[t][j] = fmaf(xv.y, av[j].y, acc[t][j]);
        acc[t][j] = fmaf(xv.z, av[j].z, acc[t][j]);
        acc[t][j] = fmaf(xv.w, av[j].w, acc[t][j]);
      }
    }
    cur ^= 1;
  }
  __syncthreads();

  // Cross-lane reduce: 64 accs/lane, 4 rounds of 16. Writes stride-1 (clean),
  // reads stride-66 by 16 lanes (16 distinct banks). fp64 final sum keeps the
  // top-k ordering exact vs the reference (selection flips are fatal).
  #pragma unroll
  for (int h = 0; h < 4; ++h) {
    #pragma unroll
    for (int a = 0; a < 16; ++a)
      red[w][a][lane] = acc[4 * h + (a >> 2)][a & 3];
    __syncthreads();
    if (lane < 16) {
      double s = 0.0;
      #pragma unroll
      for (int m = 0; m < 64; ++m) s += (double)red[w][lane][m];
      int t = 4 * h + (lane >> 2);
      int r = 4 * w + (lane & 3);
      double b = s + (double)dbias[r];
      score[t][r] = fabs(b);
      yval[t][r]  = (float)s;
    }
    __syncthreads();
  }

  // ---------------- phase 2: rank-based top-8 (== jax.lax.top_k) -----------
  {
    int t = tid >> 5, i = tid & 31;  // 512 threads = 512 (t,i) pairs
    double si = score[t][i];
    int rank = 0;
    #pragma unroll
    for (int j = 0; j < RDIM; ++j) {
      double sj = score[t][j];
      rank += (sj > si) || (sj == si && j < i);
    }
    float z = (rank < KSEL) ? yval[t][i] * 2.0f : 0.0f;   // fold SCALE=2
    Zl[t * RDIM + i] = f2bf(z);
  }
  __syncthreads();

  // ---------------- phase 3: out = Z @ B^T via mfma_f32_16x16x32_bf16 ------
  // SWAPPED operands: d = mfma(B_frag, Z_frag).
  //   A-op rows  = o-cols (load B[n0+tile*16+rr][8q..])
  //   B-op cols  = tokens (load Zl[rr][8q..])
  //   D: col = lane&15 = token, row = 4q+reg = o-col  -> d[0..3] are 4
  //   CONSECUTIVE o-cols for one token => single f4 (16 B) store per tile.
  {
    const int rr = lane & 15;
    const int q  = lane >> 4;
    const int nb = w * 512;                       // wave w: cols [512w,512w+512)
    s8 zb = *(const s8*)&Zl[rr * RDIM + q * 8];   // B-operand (token col = rr)
    const float* Bp = B + (size_t)(nb + rr) * RDIM + q * 8;
    float* op = out + (size_t)(m0 + rr) * OUT_F + nb + q * 4;

    #pragma unroll
    for (int tile = 0; tile < 32; ++tile) {
      const float* bp = Bp + (size_t)tile * 16 * RDIM;
      f4 b0 = *(const f4*)bp;
      f4 b1 = *(const f4*)(bp + 4);
      s8 a;
      a[0] = f2bf(b0.x); a[1] = f2bf(b0.y); a[2] = f2bf(b0.z); a[3] = f2bf(b0.w);
      a[4] = f2bf(b1.x); a[5] = f2bf(b1.y); a[6] = f2bf(b1.z); a[7] = f2bf(b1.w);
      cf4 d = {0.f, 0.f, 0.f, 0.f};
      d = __builtin_amdgcn_mfma_f32_16x16x32_bf16(a, zb, d, 0, 0, 0);
      *(f4*)(op + tile * 16) = *(const f4*)&d;    // 16 B contiguous store
    }
  }
}

extern "C" void kernel_launch(void* const* d_in, const int* in_sizes, int n_in,
                              void* d_out, int out_size, void* d_ws, size_t ws_size,
                              hipStream_t stream) {
  const float* x     = (const float*)d_in[0];
  const float* A     = (const float*)d_in[1];
  const float* B     = (const float*)d_in[2];
  const float* dbias = (const float*)d_in[3];
  float* out = (float*)d_out;
  (void)d_ws; (void)ws_size;

  hipLaunchKernelGGL(fused_flylora, dim3(1024), dim3(512), 0, stream,
                     x, A, B, dbias, out);
}